// Round 2
// baseline (144.909 us; speedup 1.0000x reference)
//
#include <hip/hip_runtime.h>
#include <hip/hip_bf16.h>

#define T_TOK 2048
#define DDIM  1024
#define IDIM  1024
#define NEXP  8
#define TOPK  2
#define MAXROWS (T_TOK * TOPK)

#define BM 64
#define BN 64
#define BK 32
#define LDT 40  // padded LDS row pitch in bf16 elems (80 B) -> stride-5 16B slots, conflict-free-ish

typedef __attribute__((ext_vector_type(8))) short          s16x8;
typedef __attribute__((ext_vector_type(8))) unsigned short u16x8;
typedef __attribute__((ext_vector_type(4))) float          f32x4;

__device__ __forceinline__ unsigned short f2bf(float f) {
    unsigned int u = __builtin_bit_cast(unsigned int, f);
    unsigned int r = 0x7fffu + ((u >> 16) & 1u);
    return (unsigned short)((u + r) >> 16);
}

// ---------------- routing: build per-expert compact token lists ----------------
// token_mask may arrive as uint8 (numpy bool) or int32 (harness int conversion).
// Detect: scan the first T_TOK bytes (valid under BOTH layouts). If any byte at
// position i%4!=0 is nonzero -> uint8 layout; else int32 layout.
__global__ void route_kernel(const int* __restrict__ indices,
                             const float* __restrict__ weights,
                             const void* __restrict__ mask,
                             int* __restrict__ counts, int* __restrict__ offsets,
                             int* __restrict__ tok, float* __restrict__ wslot) {
    __shared__ int cnt[NEXP], offs[NEXP], cur[NEXP];
    __shared__ int is_u8;
    const int tid = threadIdx.x;
    const unsigned char* m8  = (const unsigned char*)mask;
    const int*           m32 = (const int*)mask;
    if (tid < NEXP) cnt[tid] = 0;
    if (tid == 0) is_u8 = 0;
    __syncthreads();
    int found = 0;
    for (int i = tid; i < T_TOK; i += blockDim.x)
        if ((i & 3) != 0 && m8[i] != 0) found = 1;
    if (found) atomicOr(&is_u8, 1);
    __syncthreads();
    const int u8mode = is_u8;
    for (int idx = tid; idx < MAXROWS; idx += blockDim.x) {
        int t = idx >> 1;  // K = 2
        int active = u8mode ? (m8[t] != 0) : (m32[t] != 0);
        if (active) atomicAdd(&cnt[indices[idx]], 1);
    }
    __syncthreads();
    if (tid == 0) {
        int run = 0;
        for (int e = 0; e < NEXP; ++e) { offs[e] = run; run += cnt[e]; }
    }
    __syncthreads();
    if (tid < NEXP) { counts[tid] = cnt[tid]; offsets[tid] = offs[tid]; cur[tid] = offs[tid]; }
    __syncthreads();
    for (int idx = tid; idx < MAXROWS; idx += blockDim.x) {
        int t = idx >> 1;
        int active = u8mode ? (m8[t] != 0) : (m32[t] != 0);
        if (active) {
            int e = indices[idx];
            int p = atomicAdd(&cur[e], 1);
            tok[p]   = t;
            wslot[p] = weights[idx];
        }
    }
}

// ---------------- x: f32 -> bf16 once ----------------
__global__ __launch_bounds__(256) void cvt_x_kernel(const float* __restrict__ x,
                                                    unsigned short* __restrict__ xb) {
    int i = (blockIdx.x * 256 + threadIdx.x) * 8;
    float4 a = *reinterpret_cast<const float4*>(x + i);
    float4 b = *reinterpret_cast<const float4*>(x + i + 4);
    u16x8 v;
    v[0] = f2bf(a.x); v[1] = f2bf(a.y); v[2] = f2bf(a.z); v[3] = f2bf(a.w);
    v[4] = f2bf(b.x); v[5] = f2bf(b.y); v[6] = f2bf(b.z); v[7] = f2bf(b.w);
    *reinterpret_cast<u16x8*>(xb + i) = v;
}

// ---------------- GEMM1: H = silu(X G^T) * (X U^T), per expert ----------------
__global__ __launch_bounds__(256) void gemm1_kernel(
    const unsigned short* __restrict__ xb,
    const float* __restrict__ gate, const float* __restrict__ up,
    const int* __restrict__ counts, const int* __restrict__ offsets,
    const int* __restrict__ tok, unsigned short* __restrict__ hb) {
    const int e     = blockIdx.z;
    const int n_e   = counts[e];
    const int tileM = blockIdx.y;
    if (tileM * BM >= n_e) return;
    const int off = offsets[e];
    const int n0  = blockIdx.x * BN;

    __shared__ unsigned short lA[BM * LDT];
    __shared__ unsigned short lG[BN * LDT];
    __shared__ unsigned short lU[BN * LDT];

    const int tid  = threadIdx.x;
    const int lane = tid & 63;
    const int wid  = tid >> 6;
    const int wm   = wid >> 1, wn = wid & 1;

    // staging: thread -> (row, 8-elem segment)
    const int sr = tid >> 2, sseg = tid & 3;
    const int rowIdx = tileM * BM + sr;
    const int tIdx = (rowIdx < n_e) ? tok[off + rowIdx] : tok[off];
    const unsigned short* aSrc = xb + (size_t)tIdx * DDIM + sseg * 8;
    const float* gSrc = gate + ((size_t)e * IDIM + n0 + sr) * DDIM + sseg * 8;
    const float* uSrc = up   + ((size_t)e * IDIM + n0 + sr) * DDIM + sseg * 8;

    f32x4 accg[2][2] = {};
    f32x4 accu[2][2] = {};

    const int fr  = lane & 15;
    const int fkb = (lane >> 4) * 8;
    const unsigned short* lA0 = &lA[(wm * 32 + fr) * LDT + fkb];
    const unsigned short* lG0 = &lG[(wn * 32 + fr) * LDT + fkb];
    const unsigned short* lU0 = &lU[(wn * 32 + fr) * LDT + fkb];

    for (int k0 = 0; k0 < DDIM; k0 += BK) {
        uint4  av = *reinterpret_cast<const uint4*>(aSrc + k0);
        float4 g0 = *reinterpret_cast<const float4*>(gSrc + k0);
        float4 g1 = *reinterpret_cast<const float4*>(gSrc + k0 + 4);
        float4 u0 = *reinterpret_cast<const float4*>(uSrc + k0);
        float4 u1 = *reinterpret_cast<const float4*>(uSrc + k0 + 4);
        *reinterpret_cast<uint4*>(&lA[sr * LDT + sseg * 8]) = av;
        u16x8 gv, uv;
        gv[0] = f2bf(g0.x); gv[1] = f2bf(g0.y); gv[2] = f2bf(g0.z); gv[3] = f2bf(g0.w);
        gv[4] = f2bf(g1.x); gv[5] = f2bf(g1.y); gv[6] = f2bf(g1.z); gv[7] = f2bf(g1.w);
        uv[0] = f2bf(u0.x); uv[1] = f2bf(u0.y); uv[2] = f2bf(u0.z); uv[3] = f2bf(u0.w);
        uv[4] = f2bf(u1.x); uv[5] = f2bf(u1.y); uv[6] = f2bf(u1.z); uv[7] = f2bf(u1.w);
        *reinterpret_cast<u16x8*>(&lG[sr * LDT + sseg * 8]) = gv;
        *reinterpret_cast<u16x8*>(&lU[sr * LDT + sseg * 8]) = uv;
        __syncthreads();
        s16x8 a0 = *reinterpret_cast<const s16x8*>(lA0);
        s16x8 a1 = *reinterpret_cast<const s16x8*>(lA0 + 16 * LDT);
        s16x8 bg0 = *reinterpret_cast<const s16x8*>(lG0);
        s16x8 bg1 = *reinterpret_cast<const s16x8*>(lG0 + 16 * LDT);
        s16x8 bu0 = *reinterpret_cast<const s16x8*>(lU0);
        s16x8 bu1 = *reinterpret_cast<const s16x8*>(lU0 + 16 * LDT);
        accg[0][0] = __builtin_amdgcn_mfma_f32_16x16x32_bf16(a0, bg0, accg[0][0], 0, 0, 0);
        accg[0][1] = __builtin_amdgcn_mfma_f32_16x16x32_bf16(a0, bg1, accg[0][1], 0, 0, 0);
        accg[1][0] = __builtin_amdgcn_mfma_f32_16x16x32_bf16(a1, bg0, accg[1][0], 0, 0, 0);
        accg[1][1] = __builtin_amdgcn_mfma_f32_16x16x32_bf16(a1, bg1, accg[1][1], 0, 0, 0);
        accu[0][0] = __builtin_amdgcn_mfma_f32_16x16x32_bf16(a0, bu0, accu[0][0], 0, 0, 0);
        accu[0][1] = __builtin_amdgcn_mfma_f32_16x16x32_bf16(a0, bu1, accu[0][1], 0, 0, 0);
        accu[1][0] = __builtin_amdgcn_mfma_f32_16x16x32_bf16(a1, bu0, accu[1][0], 0, 0, 0);
        accu[1][1] = __builtin_amdgcn_mfma_f32_16x16x32_bf16(a1, bu1, accu[1][1], 0, 0, 0);
        __syncthreads();
    }

    const int rbase = tileM * BM;
#pragma unroll
    for (int m = 0; m < 2; ++m)
#pragma unroll
        for (int n = 0; n < 2; ++n)
#pragma unroll
            for (int j = 0; j < 4; ++j) {
                int rl = wm * 32 + m * 16 + (lane >> 4) * 4 + j;
                if (rbase + rl < n_e) {
                    int col = wn * 32 + n * 16 + (lane & 15);
                    float g = accg[m][n][j];
                    float u = accu[m][n][j];
                    float h = (g / (1.0f + __expf(-g))) * u;
                    hb[(size_t)(off + rbase + rl) * IDIM + n0 + col] = f2bf(h);
                }
            }
}

// ---------------- GEMM2: Y_rows = H D^T, weighted scatter-add into y ----------------
__global__ __launch_bounds__(256) void gemm2_kernel(
    const unsigned short* __restrict__ hb, const float* __restrict__ down,
    const int* __restrict__ counts, const int* __restrict__ offsets,
    const int* __restrict__ tok, const float* __restrict__ wslot,
    float* __restrict__ y) {
    const int e     = blockIdx.z;
    const int n_e   = counts[e];
    const int tileM = blockIdx.y;
    if (tileM * BM >= n_e) return;
    const int off = offsets[e];
    const int n0  = blockIdx.x * BN;

    __shared__ unsigned short lA[BM * LDT];
    __shared__ unsigned short lB[BN * LDT];

    const int tid  = threadIdx.x;
    const int lane = tid & 63;
    const int wid  = tid >> 6;
    const int wm   = wid >> 1, wn = wid & 1;

    const int sr = tid >> 2, sseg = tid & 3;
    const int rowIdx = tileM * BM + sr;
    const int hrow = (rowIdx < n_e) ? (off + rowIdx) : off;
    const unsigned short* aSrc = hb + (size_t)hrow * IDIM + sseg * 8;
    const float* bSrc = down + ((size_t)e * DDIM + n0 + sr) * IDIM + sseg * 8;

    f32x4 acc[2][2] = {};

    const int fr  = lane & 15;
    const int fkb = (lane >> 4) * 8;
    const unsigned short* lA0 = &lA[(wm * 32 + fr) * LDT + fkb];
    const unsigned short* lB0 = &lB[(wn * 32 + fr) * LDT + fkb];

    for (int k0 = 0; k0 < IDIM; k0 += BK) {
        uint4  av = *reinterpret_cast<const uint4*>(aSrc + k0);
        float4 b0 = *reinterpret_cast<const float4*>(bSrc + k0);
        float4 b1 = *reinterpret_cast<const float4*>(bSrc + k0 + 4);
        *reinterpret_cast<uint4*>(&lA[sr * LDT + sseg * 8]) = av;
        u16x8 bv;
        bv[0] = f2bf(b0.x); bv[1] = f2bf(b0.y); bv[2] = f2bf(b0.z); bv[3] = f2bf(b0.w);
        bv[4] = f2bf(b1.x); bv[5] = f2bf(b1.y); bv[6] = f2bf(b1.z); bv[7] = f2bf(b1.w);
        *reinterpret_cast<u16x8*>(&lB[sr * LDT + sseg * 8]) = bv;
        __syncthreads();
        s16x8 a0 = *reinterpret_cast<const s16x8*>(lA0);
        s16x8 a1 = *reinterpret_cast<const s16x8*>(lA0 + 16 * LDT);
        s16x8 b0f = *reinterpret_cast<const s16x8*>(lB0);
        s16x8 b1f = *reinterpret_cast<const s16x8*>(lB0 + 16 * LDT);
        acc[0][0] = __builtin_amdgcn_mfma_f32_16x16x32_bf16(a0, b0f, acc[0][0], 0, 0, 0);
        acc[0][1] = __builtin_amdgcn_mfma_f32_16x16x32_bf16(a0, b1f, acc[0][1], 0, 0, 0);
        acc[1][0] = __builtin_amdgcn_mfma_f32_16x16x32_bf16(a1, b0f, acc[1][0], 0, 0, 0);
        acc[1][1] = __builtin_amdgcn_mfma_f32_16x16x32_bf16(a1, b1f, acc[1][1], 0, 0, 0);
        __syncthreads();
    }

    const int rbase = tileM * BM;
#pragma unroll
    for (int m = 0; m < 2; ++m)
#pragma unroll
        for (int n = 0; n < 2; ++n)
#pragma unroll
            for (int j = 0; j < 4; ++j) {
                int rl = wm * 32 + m * 16 + (lane >> 4) * 4 + j;
                if (rbase + rl < n_e) {
                    int col = wn * 32 + n * 16 + (lane & 15);
                    int row = off + rbase + rl;
                    float v = acc[m][n][j] * wslot[row];
                    atomicAdd(&y[(size_t)tok[row] * DDIM + n0 + col], v);
                }
            }
}

extern "C" void kernel_launch(void* const* d_in, const int* in_sizes, int n_in,
                              void* d_out, int out_size, void* d_ws, size_t ws_size,
                              hipStream_t stream) {
    const float* x       = (const float*)d_in[0];
    const void*  mask    = d_in[1];
    const float* weights = (const float*)d_in[2];
    const int*   indices = (const int*)d_in[3];
    const float* gate    = (const float*)d_in[4];
    const float* up      = (const float*)d_in[5];
    const float* down    = (const float*)d_in[6];
    float*       y       = (float*)d_out;

    char* ws = (char*)d_ws;
    int*            counts  = (int*)ws;
    int*            offsets = (int*)(ws + 32);
    int*            tok     = (int*)(ws + 256);
    float*          wslot   = (float*)(ws + 256 + MAXROWS * 4);
    unsigned short* xb      = (unsigned short*)(ws + 65536);
    unsigned short* hb      = (unsigned short*)(ws + 65536 + (size_t)T_TOK * DDIM * 2);

    hipMemsetAsync(d_out, 0, (size_t)out_size * sizeof(float), stream);
    route_kernel<<<1, 256, 0, stream>>>(indices, weights, mask, counts, offsets, tok, wslot);
    cvt_x_kernel<<<(T_TOK * DDIM / 8) / 256, 256, 0, stream>>>(x, xb);

    dim3 g1(IDIM / BN, MAXROWS / BM, NEXP);
    gemm1_kernel<<<g1, 256, 0, stream>>>(xb, gate, up, counts, offsets, tok, hb);
    dim3 g2(DDIM / BN, MAXROWS / BM, NEXP);
    gemm2_kernel<<<g2, 256, 0, stream>>>(hb, down, counts, offsets, tok, wslot, y);
}